// Round 2
// baseline (778.914 us; speedup 1.0000x reference)
//
#include <hip/hip_runtime.h>
#include <hip/hip_bf16.h>

#define NN 4096     // layer size n
#define RR 4        // displacement rank
#define BB 8192     // batch
#define CHUNK 64            // t-chunk for prefix kernels
#define NCHUNK (NN / CHUNK) // 64

typedef __bf16 bf16x8 __attribute__((ext_vector_type(8)));
typedef float f32x4 __attribute__((ext_vector_type(4)));
typedef unsigned short u16;
typedef unsigned int u32;

#define GLOBAL_AS(p) ((const __attribute__((address_space(1))) u32*)(p))
#define LDS_AS(p) ((__attribute__((address_space(3))) u32*)(p))

// ---------------------------------------------------------------------------
// Kernel 0: cast x (f32) -> bf16, 8 elements/thread, fully vectorized.
// ---------------------------------------------------------------------------
__device__ inline u32 pack_bf2(float lo, float hi) {
    __hip_bfloat162 h2 = __float22bfloat162_rn(make_float2(lo, hi));
    return *(u32*)&h2;
}

__global__ void cast_x_kernel(const float* __restrict__ x, uint4* __restrict__ xb) {
    size_t i = (size_t)blockIdx.x * 256 + threadIdx.x;  // one 8-elem chunk each
    const float4* x4 = (const float4*)x;
    float4 a = x4[2 * i];
    float4 b = x4[2 * i + 1];
    uint4 o;
    o.x = pack_bf2(a.x, a.y);
    o.y = pack_bf2(a.z, a.w);
    o.z = pack_bf2(b.x, b.y);
    o.w = pack_bf2(b.z, b.w);
    xb[i] = o;
}

// ---------------------------------------------------------------------------
// Kernel 1: block sums S_T(J,d) = sum_{t in chunk J} q(d,t)   [transposed!]
//   q(d,t) = sum_r G[r][(d+t)%n] * H[r][t]
// grid: 16 d-blocks x 64 J = 1024 blocks, 256 threads. Stores coalesced.
// ---------------------------------------------------------------------------
__global__ void ksum_kernel(const float* __restrict__ G, const float* __restrict__ H,
                            float* __restrict__ S_T) {
    int dblk = blockIdx.x & 15;
    int J = blockIdx.x >> 4;
    int d = dblk * 256 + threadIdx.x;
    int t0 = J * CHUNK;
    float acc = 0.f;
#pragma unroll 4
    for (int tt = 0; tt < CHUNK; ++tt) {
        int t = t0 + tt;
        float h0 = H[t], h1 = H[NN + t], h2 = H[2 * NN + t], h3 = H[3 * NN + t];
        int idx = (d + t) & (NN - 1);
        acc += G[idx] * h0 + G[NN + idx] * h1 + G[2 * NN + idx] * h2 + G[3 * NN + idx] * h3;
    }
    S_T[J * NN + d] = acc;  // coalesced
}

// ---------------------------------------------------------------------------
// Kernel 2: prefix + W write, coalesced via LDS tile transpose.
// Block = one 64x64 output tile (rows i0..i0+63, cols t0..t0+63), 128 threads.
// Thread dl owns diagonal d = (i0 - t0 - 63 + dl) mod n, runs the 64-step
// in-chunk prefix, deposits in-tile values to LDS (stride 66 u16 -> the
// diagonal stores hit 64 distinct banks = 2-way = free). Then the tile is
// written out row-contiguous as uint4 (full 128B lines).
// ---------------------------------------------------------------------------
__global__ __launch_bounds__(128) void kprefix_kernel(const float* __restrict__ G,
                                                      const float* __restrict__ H,
                                                      const float* __restrict__ S_T,
                                                      u16* __restrict__ W) {
    __shared__ u32 tile32[64 * 33];          // [r][..] row stride 33 u32 = 66 u16
    u16* tile = (u16*)tile32;

    int itile = blockIdx.x >> 6;             // 64 row-tiles
    int J = blockIdx.x & 63;                 // 64 col-chunks
    int i0 = itile * 64, t0 = J * CHUNK;
    int dl = threadIdx.x;                    // 0..127 (dl=127 computes, never writes)
    int d = (i0 - t0 - 63 + dl) & (NN - 1);

    float pre = 0.f, tot = 0.f;
    for (int Jp = 0; Jp < NCHUNK; ++Jp) {
        float v = S_T[Jp * NN + d];          // coalesced across dl
        if (Jp < J) pre += v;
        tot += v;
    }
    float acc = pre - 0.5f * tot;

#pragma unroll 4
    for (int tt = 0; tt < CHUNK; ++tt) {
        int t = t0 + tt;
        float h0 = H[t], h1 = H[NN + t], h2 = H[2 * NN + t], h3 = H[3 * NN + t];
        int idx = (d + t) & (NN - 1);
        acc += G[idx] * h0 + G[NN + idx] * h1 + G[2 * NN + idx] * h2 + G[3 * NN + idx] * h3;
        int r = dl + tt - 63;                // in-tile row
        if ((unsigned)r < 64u) {
            __hip_bfloat16 w = __float2bfloat16(acc);
            tile[r * 66 + tt] = *(u16*)&w;
        }
    }
    __syncthreads();

    // coalesced flush: thread h -> row r=h>>1, half h&1: 32 u16 = 4 uint4
    int r = threadIdx.x >> 1, half = threadIdx.x & 1;
    const u32* src = &tile32[r * 33 + half * 16];
    uint4* dst = (uint4*)(W + (size_t)(i0 + r) * NN + t0 + half * 32);
#pragma unroll
    for (int q = 0; q < 4; ++q)
        dst[q] = make_uint4(src[4 * q], src[4 * q + 1], src[4 * q + 2], src[4 * q + 3]);
}

// ---------------------------------------------------------------------------
// Kernel 3: NT GEMM  y[b,i] = sum_j xbf[b,j] * W[i,j]   (f32 accumulate/out)
// 128x128 tile, BK=32, 4 waves, 4x4 16x16x32 MFMA per wave.
// LDS layout k-major: slot = kq*128 + row (kq = k/8). Fragment reads per
// quarter-wave are 16 consecutive 16B slots = 256 contiguous bytes = 2-way
// bank aliasing = free. global_load_lds dest = wave base + lane*16 (valid).
// ---------------------------------------------------------------------------
#define BM 128
#define BN 128
#define BK 32

__global__ __launch_bounds__(256) void gemm_bt_kernel(const u16* __restrict__ A,   // x bf16, M x K
                                                      const u16* __restrict__ Bm,  // W bf16, N x K
                                                      float* __restrict__ C) {
    constexpr int N = NN, K = NN;
    __shared__ __align__(16) u16 As[BM * BK];
    __shared__ __align__(16) u16 Bs[BN * BK];

    int tid = threadIdx.x;
    int bx = blockIdx.x % (N / BN);  // 32 tiles along N
    int by = blockIdx.x / (N / BN);  // 64 tiles along M
    int m0 = by * BM, n0 = bx * BN;
    int wave = tid >> 6, lane = tid & 63;
    int wm = (wave >> 1) * 64, wn = (wave & 1) * 64;
    int lrow = lane & 15, lq = lane >> 4;

    f32x4 acc[4][4] = {};

    // staging chunk c in [0,512): kq = c>>7 (k-octet), row = c&127
    int c0 = tid, c1 = tid + 256;
    const u16* gA0 = A + (size_t)(m0 + (c0 & 127)) * K + ((c0 >> 7) << 3);
    const u16* gA1 = A + (size_t)(m0 + (c1 & 127)) * K + ((c1 >> 7) << 3);
    const u16* gB0 = Bm + (size_t)(n0 + (c0 & 127)) * K + ((c0 >> 7) << 3);
    const u16* gB1 = Bm + (size_t)(n0 + (c1 & 127)) * K + ((c1 >> 7) << 3);

    for (int k0 = 0; k0 < K; k0 += BK) {
        __builtin_amdgcn_global_load_lds(GLOBAL_AS(gA0 + k0), LDS_AS((char*)As + c0 * 16), 16, 0, 0);
        __builtin_amdgcn_global_load_lds(GLOBAL_AS(gA1 + k0), LDS_AS((char*)As + c1 * 16), 16, 0, 0);
        __builtin_amdgcn_global_load_lds(GLOBAL_AS(gB0 + k0), LDS_AS((char*)Bs + c0 * 16), 16, 0, 0);
        __builtin_amdgcn_global_load_lds(GLOBAL_AS(gB1 + k0), LDS_AS((char*)Bs + c1 * 16), 16, 0, 0);
        __builtin_amdgcn_s_waitcnt(0x0f70);  // vmcnt(0)
        __syncthreads();

        bf16x8 af[4], bfr[4];
#pragma unroll
        for (int i = 0; i < 4; ++i)  // slot = lq*128 + (wm + i*16 + lrow)
            af[i] = *(const bf16x8*)&As[((lq << 7) + wm + i * 16 + lrow) << 3];
#pragma unroll
        for (int i = 0; i < 4; ++i)
            bfr[i] = *(const bf16x8*)&Bs[((lq << 7) + wn + i * 16 + lrow) << 3];
#pragma unroll
        for (int i = 0; i < 4; ++i)
#pragma unroll
            for (int j = 0; j < 4; ++j)
                acc[i][j] = __builtin_amdgcn_mfma_f32_16x16x32_bf16(af[i], bfr[j], acc[i][j], 0, 0, 0);
        __syncthreads();
    }

    // epilogue: D layout col=lane&15, row=(lane>>4)*4+e
#pragma unroll
    for (int i = 0; i < 4; ++i)
#pragma unroll
        for (int j = 0; j < 4; ++j)
#pragma unroll
            for (int e = 0; e < 4; ++e) {
                int row = m0 + wm + i * 16 + lq * 4 + e;
                int col = n0 + wn + j * 16 + lrow;
                C[(size_t)row * N + col] = acc[i][j][e];
            }
}

// ---------------------------------------------------------------------------
extern "C" void kernel_launch(void* const* d_in, const int* in_sizes, int n_in,
                              void* d_out, int out_size, void* d_ws, size_t ws_size,
                              hipStream_t stream) {
    const float* x = (const float*)d_in[0];
    const float* G = (const float*)d_in[1];
    const float* H = (const float*)d_in[2];
    float* y = (float*)d_out;

    char* ws = (char*)d_ws;
    u16* xbf = (u16*)ws;                                   // 64 MB
    u16* Wbf = (u16*)(ws + (size_t)BB * NN * 2);           // 32 MB
    float* S_T = (float*)(ws + (size_t)BB * NN * 2 + (size_t)NN * NN * 2);  // 1 MB

    hipLaunchKernelGGL(cast_x_kernel, dim3((BB * NN / 8) / 256), dim3(256), 0, stream, x, (uint4*)xbf);
    hipLaunchKernelGGL(ksum_kernel, dim3((NN / 256) * NCHUNK), dim3(256), 0, stream, G, H, S_T);
    hipLaunchKernelGGL(kprefix_kernel, dim3(64 * 64), dim3(128), 0, stream, G, H, S_T, Wbf);
    hipLaunchKernelGGL(gemm_bt_kernel, dim3((BB / BM) * (NN / BN)), dim3(256), 0, stream, xbf, Wbf, y);
}

// Round 3
// 609.188 us; speedup vs baseline: 1.2786x; 1.2786x over previous
//
#include <hip/hip_runtime.h>
#include <hip/hip_bf16.h>

#define NN 4096     // layer size n
#define RR 4        // displacement rank
#define BB 8192     // batch
#define CHUNK 64            // t-chunk for prefix kernels
#define NCHUNK (NN / CHUNK) // 64

typedef __bf16 bf16x8 __attribute__((ext_vector_type(8)));
typedef float f32x4 __attribute__((ext_vector_type(4)));
typedef unsigned short u16;
typedef unsigned int u32;

#define GLOBAL_AS(p) ((const __attribute__((address_space(1))) u32*)(p))
#define LDS_AS(p) ((__attribute__((address_space(3))) u32*)(p))

// Tiled bf16 staging layout (matches GEMM LDS slot order exactly):
//   buf[tile128][k_blk][kq][row][8]   (slot = kq*128 + row, 512 slots/k_blk)
// so each global_load_lds_dwordx4 wave-instruction reads 1 KB contiguous.

__device__ inline u32 pack_bf2(float lo, float hi) {
    __hip_bfloat162 h2 = __float22bfloat162_rn(make_float2(lo, hi));
    return *(u32*)&h2;
}

// ---------------------------------------------------------------------------
// Kernel 0: cast x (f32, row-major) -> bf16 tiled layout.
// Block = one 128-row x 32-col tile, 256 threads, 8KB LDS round-trip.
// Reads: 8 lanes cover one row's 128 B = full cache lines. Writes: contiguous.
// ---------------------------------------------------------------------------
__global__ __launch_bounds__(256) void cast_x_kernel(const float* __restrict__ x,
                                                     uint4* __restrict__ xt) {
    __shared__ u32 lds[512 * 4];           // 512 slots x 16 B
    int mt = blockIdx.x >> 7;              // 64 m-tiles
    int kb = blockIdx.x & 127;             // 128 k-blocks
    int t = threadIdx.x;
    const float4* x4 = (const float4*)x;
    int col = t & 7, rsub = t >> 3;        // 8 float4-cols x 32 rows per pass
    int kq = col >> 1, half = col & 1;
#pragma unroll
    for (int rr = 0; rr < 4; ++rr) {
        int row = rr * 32 + rsub;
        float4 v = x4[(size_t)(mt * 128 + row) * (NN / 4) + kb * 8 + col];
        int slot = kq * 128 + row;
        lds[slot * 4 + half * 2] = pack_bf2(v.x, v.y);
        lds[slot * 4 + half * 2 + 1] = pack_bf2(v.z, v.w);
    }
    __syncthreads();
    const uint4* l4 = (const uint4*)lds;
    size_t base = ((size_t)mt * 128 + kb) * 512;
    xt[base + t] = l4[t];
    xt[base + t + 256] = l4[t + 256];
}

// ---------------------------------------------------------------------------
// Kernel 1: block sums S_T(J,d) = sum_{t in chunk J} q(d,t)
//   q(d,t) = sum_r G[r][(d+t)%n] * H[r][t]
// ---------------------------------------------------------------------------
__global__ void ksum_kernel(const float* __restrict__ G, const float* __restrict__ H,
                            float* __restrict__ S_T) {
    int dblk = blockIdx.x & 15;
    int J = blockIdx.x >> 4;
    int d = dblk * 256 + threadIdx.x;
    int t0 = J * CHUNK;
    float acc = 0.f;
#pragma unroll 4
    for (int tt = 0; tt < CHUNK; ++tt) {
        int t = t0 + tt;
        float h0 = H[t], h1 = H[NN + t], h2 = H[2 * NN + t], h3 = H[3 * NN + t];
        int idx = (d + t) & (NN - 1);
        acc += G[idx] * h0 + G[NN + idx] * h1 + G[2 * NN + idx] * h2 + G[3 * NN + idx] * h3;
    }
    S_T[J * NN + d] = acc;  // coalesced
}

// ---------------------------------------------------------------------------
// Kernel 2: prefix + W write (bf16 tiled layout) via LDS tile transpose.
// Block = one 64x64 W tile (rows i0.., cols t0..), 128 threads.
// ---------------------------------------------------------------------------
__global__ __launch_bounds__(128) void kprefix_kernel(const float* __restrict__ G,
                                                      const float* __restrict__ H,
                                                      const float* __restrict__ S_T,
                                                      uint4* __restrict__ Wt) {
    __shared__ u32 tile32[64 * 33];          // row stride 33 u32 = 66 u16
    u16* tile = (u16*)tile32;

    int itile = blockIdx.x >> 6;             // 64 row-tiles
    int J = blockIdx.x & 63;                 // 64 col-chunks
    int i0 = itile * 64, t0 = J * CHUNK;
    int dl = threadIdx.x;                    // 0..127
    int d = (i0 - t0 - 63 + dl) & (NN - 1);

    float pre = 0.f, tot = 0.f;
    for (int Jp = 0; Jp < NCHUNK; ++Jp) {
        float v = S_T[Jp * NN + d];          // coalesced across dl
        if (Jp < J) pre += v;
        tot += v;
    }
    float acc = pre - 0.5f * tot;

#pragma unroll 4
    for (int tt = 0; tt < CHUNK; ++tt) {
        int t = t0 + tt;
        float h0 = H[t], h1 = H[NN + t], h2 = H[2 * NN + t], h3 = H[3 * NN + t];
        int idx = (d + t) & (NN - 1);
        acc += G[idx] * h0 + G[NN + idx] * h1 + G[2 * NN + idx] * h2 + G[3 * NN + idx] * h3;
        int r = dl + tt - 63;                // in-tile row
        if ((unsigned)r < 64u) {
            __hip_bfloat16 w = __float2bfloat16(acc);
            tile[r * 66 + tt] = *(u16*)&w;
        }
    }
    __syncthreads();

    // flush into tiled layout: thread h -> row r=h>>1, 32-col half h&1
    int r = threadIdx.x >> 1, half = threadIdx.x & 1;
    const u32* src = &tile32[r * 33 + half * 16];
    int gr = i0 + r;                         // global W row (the "n" dim)
    int nt = gr >> 7, row128 = gr & 127;
    int kb = J * 2 + half;                   // 32-col k-block index
    size_t sb = ((size_t)nt * 128 + kb) * 512 + row128;
#pragma unroll
    for (int q = 0; q < 4; ++q)              // kq = q, slots stride 128
        Wt[sb + (size_t)q * 128] = make_uint4(src[4 * q], src[4 * q + 1],
                                              src[4 * q + 2], src[4 * q + 3]);
}

// ---------------------------------------------------------------------------
// Kernel 3: NT GEMM  y[b,i] = sum_j xbf[b,j] * W[i,j]  (f32 out)
// 128x128 tile, BK=32, 4 waves, 4x4 16x16x32 MFMA.
// Tiled operands: every global_load_lds instruction = 1 KB contiguous.
// LDS k-major (slot = kq*128+row): fragment ds_read_b128 conflict-free.
// ---------------------------------------------------------------------------
#define BM 128
#define BN 128
#define BK 32

__global__ __launch_bounds__(256) void gemm_bt_kernel(const u16* __restrict__ At,
                                                      const u16* __restrict__ Bt,
                                                      float* __restrict__ C) {
    constexpr int N = NN, K = NN;
    __shared__ __align__(16) u16 As[BM * BK];
    __shared__ __align__(16) u16 Bs[BN * BK];

    int tid = threadIdx.x;
    int bx = blockIdx.x % (N / BN);  // 32 tiles along N
    int by = blockIdx.x / (N / BN);  // 64 tiles along M
    int wave = tid >> 6, lane = tid & 63;
    int wm = (wave >> 1) * 64, wn = (wave & 1) * 64;
    int lrow = lane & 15, lq = lane >> 4;

    f32x4 acc[4][4] = {};

    int c0 = tid, c1 = tid + 256;
    // tile base: by (resp. bx) selects 128 rows; 128 k-blocks x 512 slots x 8 u16
    const u16* gA0 = At + (size_t)by * 524288 + (size_t)c0 * 8;
    const u16* gA1 = gA0 + 2048;   // c1 = c0 + 256 slots
    const u16* gB0 = Bt + (size_t)bx * 524288 + (size_t)c0 * 8;
    const u16* gB1 = gB0 + 2048;

    for (int kb = 0; kb < K / BK; ++kb) {
        size_t off = (size_t)kb * 4096;  // 512 slots * 8 u16 per k-block
        __builtin_amdgcn_global_load_lds(GLOBAL_AS(gA0 + off), LDS_AS((char*)As + c0 * 16), 16, 0, 0);
        __builtin_amdgcn_global_load_lds(GLOBAL_AS(gA1 + off), LDS_AS((char*)As + c1 * 16), 16, 0, 0);
        __builtin_amdgcn_global_load_lds(GLOBAL_AS(gB0 + off), LDS_AS((char*)Bs + c0 * 16), 16, 0, 0);
        __builtin_amdgcn_global_load_lds(GLOBAL_AS(gB1 + off), LDS_AS((char*)Bs + c1 * 16), 16, 0, 0);
        __builtin_amdgcn_s_waitcnt(0x0f70);  // vmcnt(0)
        __syncthreads();

        bf16x8 af[4], bfr[4];
#pragma unroll
        for (int i = 0; i < 4; ++i)  // slot = lq*128 + (wm + i*16 + lrow)
            af[i] = *(const bf16x8*)&As[((lq << 7) + wm + i * 16 + lrow) << 3];
#pragma unroll
        for (int i = 0; i < 4; ++i)
            bfr[i] = *(const bf16x8*)&Bs[((lq << 7) + wn + i * 16 + lrow) << 3];
#pragma unroll
        for (int i = 0; i < 4; ++i)
#pragma unroll
            for (int j = 0; j < 4; ++j)
                acc[i][j] = __builtin_amdgcn_mfma_f32_16x16x32_bf16(af[i], bfr[j], acc[i][j], 0, 0, 0);
        __syncthreads();
    }

    int m0 = by * BM, n0 = bx * BN;
    // epilogue: D layout col=lane&15, row=(lane>>4)*4+e
#pragma unroll
    for (int i = 0; i < 4; ++i)
#pragma unroll
        for (int j = 0; j < 4; ++j)
#pragma unroll
            for (int e = 0; e < 4; ++e) {
                int row = m0 + wm + i * 16 + lq * 4 + e;
                int col = n0 + wn + j * 16 + lrow;
                C[(size_t)row * N + col] = acc[i][j][e];
            }
}

// ---------------------------------------------------------------------------
extern "C" void kernel_launch(void* const* d_in, const int* in_sizes, int n_in,
                              void* d_out, int out_size, void* d_ws, size_t ws_size,
                              hipStream_t stream) {
    const float* x = (const float*)d_in[0];
    const float* G = (const float*)d_in[1];
    const float* H = (const float*)d_in[2];
    float* y = (float*)d_out;

    char* ws = (char*)d_ws;
    u16* xbf = (u16*)ws;                                   // 64 MB, tiled
    u16* Wbf = (u16*)(ws + (size_t)BB * NN * 2);           // 32 MB, tiled
    float* S_T = (float*)(ws + (size_t)BB * NN * 2 + (size_t)NN * NN * 2);  // 1 MB

    hipLaunchKernelGGL(cast_x_kernel, dim3((BB / 128) * (NN / 32)), dim3(256), 0, stream,
                       x, (uint4*)xbf);
    hipLaunchKernelGGL(ksum_kernel, dim3((NN / 256) * NCHUNK), dim3(256), 0, stream, G, H, S_T);
    hipLaunchKernelGGL(kprefix_kernel, dim3(64 * 64), dim3(128), 0, stream, G, H, S_T,
                       (uint4*)Wbf);
    hipLaunchKernelGGL(gemm_bt_kernel, dim3((BB / BM) * (NN / BN)), dim3(256), 0, stream,
                       xbf, Wbf, y);
}